// Round 1
// baseline (459.577 us; speedup 1.0000x reference)
//
#include <hip/hip_runtime.h>
#include <stdint.h>
#include <math.h>

#define DEVI __device__ __forceinline__

typedef __attribute__((ext_vector_type(8))) short bf16x8;
typedef __attribute__((ext_vector_type(4))) float f32x4;

DEVI unsigned short f2bf(float f) {
  union { float f; unsigned u; } v; v.f = f;
  unsigned u = v.u;
  u += 0x7fffu + ((u >> 16) & 1u);   // round-to-nearest-even
  return (unsigned short)(u >> 16);
}

DEVI f32x4 mfma16(bf16x8 a, bf16x8 b, f32x4 c) {
  return __builtin_amdgcn_mfma_f32_16x16x32_bf16(a, b, c, 0, 0, 0);
}

// ---------------- fp32 -> bf16 convert ----------------
__global__ __launch_bounds__(256) void cvt_kernel(const float* __restrict__ in,
                                                  unsigned short* __restrict__ out, int n) {
  int i = (blockIdx.x * 256 + threadIdx.x) * 4;
  if (i < n) {
    float4 v = *(const float4*)(in + i);
    unsigned lo = f2bf(v.x) | ((unsigned)f2bf(v.y) << 16);
    unsigned hi = f2bf(v.z) | ((unsigned)f2bf(v.w) << 16);
    uint2 o; o.x = lo; o.y = hi;
    *(uint2*)(out + i) = o;
  }
}

// ---------------- GEMM: C[M,N] = A[M,K] * Bw[N,K]^T + bias ----------------
// MODE 0: scatter bf16 output to Q/K/V [B,H,T,hd]   MODE 1: fp32 output to Cf
template <int MODE>
__global__ __launch_bounds__(256) void gemm_bt(
    const unsigned short* __restrict__ A, const unsigned short* __restrict__ Bw,
    const float* __restrict__ bias, float* __restrict__ Cf,
    unsigned short* __restrict__ Qo, unsigned short* __restrict__ Ko,
    unsigned short* __restrict__ Vo, int M, int N, int K) {
  __shared__ unsigned short As[128 * 64];
  __shared__ unsigned short Bs[128 * 64];
  const int tid = threadIdx.x;
  const int lane = tid & 63;
  const int w = tid >> 6;
  const int wm = w & 1, wn = w >> 1;
  const int lr = lane & 15, lq = lane >> 4;
  const int m0 = blockIdx.y * 128;
  const int n0 = blockIdx.x * 128;

  f32x4 acc[4][4] = {};

  for (int kt = 0; kt < K; kt += 64) {
    __syncthreads();
#pragma unroll
    for (int i = 0; i < 4; ++i) {
      int c = i * 256 + tid;
      int row = c >> 3, cb = (c & 7) << 3;
      float4 av = *(const float4*)(A + (size_t)(m0 + row) * K + kt + cb);
      *(float4*)(&As[row * 64 + cb]) = av;
      float4 bv = *(const float4*)(Bw + (size_t)(n0 + row) * K + kt + cb);
      *(float4*)(&Bs[row * 64 + cb]) = bv;
    }
    __syncthreads();
#pragma unroll
    for (int kk = 0; kk < 64; kk += 32) {
      bf16x8 af[4], bfr[4];
#pragma unroll
      for (int mt = 0; mt < 4; ++mt)
        af[mt] = *(const bf16x8*)(&As[(wm * 64 + mt * 16 + lr) * 64 + kk + lq * 8]);
#pragma unroll
      for (int nt = 0; nt < 4; ++nt)
        bfr[nt] = *(const bf16x8*)(&Bs[(wn * 64 + nt * 16 + lr) * 64 + kk + lq * 8]);
#pragma unroll
      for (int mt = 0; mt < 4; ++mt)
#pragma unroll
        for (int nt = 0; nt < 4; ++nt)
          acc[mt][nt] = mfma16(af[mt], bfr[nt], acc[mt][nt]);
    }
  }

#pragma unroll
  for (int mt = 0; mt < 4; ++mt) {
#pragma unroll
    for (int nt = 0; nt < 4; ++nt) {
      int n_g = n0 + wn * 64 + nt * 16 + lr;
      float bv = bias[n_g];
#pragma unroll
      for (int r = 0; r < 4; ++r) {
        int m_g = m0 + wm * 64 + mt * 16 + lq * 4 + r;
        float v = acc[mt][nt][r] + bv;
        if (MODE == 1) {
          Cf[(size_t)m_g * N + n_g] = v;
        } else {
          int which = n_g >> 10;               // 0:Q 1:K 2:V  (uniform per block)
          int rem = n_g & 1023;
          int h = rem >> 6, d = rem & 63;
          int b = m_g >> 11, t = m_g & 2047;
          size_t idx = (((size_t)(b * 16 + h) * 2048) + t) * 64 + d;
          unsigned short* p = (which == 0) ? Qo : ((which == 1) ? Ko : Vo);
          p[idx] = f2bf(v);
        }
      }
    }
  }
}

// ---------------- flash attention (causal), Br=Bc=64, hd=64 ----------------
__global__ __launch_bounds__(256) void attn_kernel(
    const unsigned short* __restrict__ Q, const unsigned short* __restrict__ K,
    const unsigned short* __restrict__ V, unsigned short* __restrict__ Y) {
  constexpr int T = 2048, HD = 64, H = 16;
  __shared__ unsigned short Kt[64 * 72];      // K rows [kv][d], pad 8
  __shared__ unsigned short Vt[64 * 72];      // V^T    [d][kv], pad 8
  __shared__ unsigned short Pt[4][16 * 72];   // per-wave P, [qrow][kv]

  const int tid = threadIdx.x;
  const int lane = tid & 63;
  const int w = tid >> 6;
  const int lr = lane & 15, lq = lane >> 4;
  const int qt = blockIdx.x;   // 0..31
  const int h = blockIdx.y;    // 0..15
  const int b = blockIdx.z;    // 0..3
  const size_t bh = (size_t)(b * H + h) * T * HD;
  const int q0 = qt * 64;

  // Q A-fragments in registers for the whole kernel
  bf16x8 qf[2];
  const int qrow = q0 + w * 16 + lr;
#pragma unroll
  for (int kb = 0; kb < 2; ++kb)
    qf[kb] = *(const bf16x8*)(Q + bh + (size_t)qrow * HD + kb * 32 + lq * 8);

  f32x4 o[4] = {};
  float mi[4], li[4];
#pragma unroll
  for (int r = 0; r < 4; ++r) { mi[r] = -INFINITY; li[r] = 0.f; }

  for (int jt = 0; jt <= qt; ++jt) {
    const int c0 = jt * 64;
    __syncthreads();   // previous tile's Kt/Vt reads done
#pragma unroll
    for (int i = 0; i < 2; ++i) {
      int c = i * 256 + tid;
      // K: row-contiguous chunks (coalesced load, b128 LDS write)
      int krow = c >> 3, kcb = (c & 7) << 3;
      float4 kv4 = *(const float4*)(K + bh + (size_t)(c0 + krow) * HD + kcb);
      *(float4*)(&Kt[krow * 72 + kcb]) = kv4;
      // V: lane-per-row chunks -> conflict-free scalar transpose writes
      int vrow = c & 63, vcb = ((c >> 6) & 7) << 3;
      float4 vv4 = *(const float4*)(V + bh + (size_t)(c0 + vrow) * HD + vcb);
      const unsigned short* vp = (const unsigned short*)&vv4;
#pragma unroll
      for (int j = 0; j < 8; ++j) Vt[(vcb + j) * 72 + vrow] = vp[j];
    }
    __syncthreads();

    // S = Q K^T (wave handles 16 q-rows x 64 kv-cols)
    f32x4 s[4];
#pragma unroll
    for (int nt = 0; nt < 4; ++nt) {
      bf16x8 kf0 = *(const bf16x8*)(&Kt[(nt * 16 + lr) * 72 + lq * 8]);
      bf16x8 kf1 = *(const bf16x8*)(&Kt[(nt * 16 + lr) * 72 + 32 + lq * 8]);
      f32x4 z = {};
      z = mfma16(qf[0], kf0, z);
      s[nt] = mfma16(qf[1], kf1, z);
    }
    const bool diag = (jt == qt);
#pragma unroll
    for (int nt = 0; nt < 4; ++nt) {
#pragma unroll
      for (int r = 0; r < 4; ++r) {
        float sv = s[nt][r] * 0.125f;   // 1/sqrt(64)
        if (diag) {
          int kv_g = c0 + nt * 16 + lr;
          int q_g = q0 + w * 16 + lq * 4 + r;
          if (kv_g > q_g) sv = -INFINITY;
        }
        s[nt][r] = sv;
      }
    }
    // online softmax: row max, alpha, p, row sum
    float mnew[4], alpha[4], rsum[4];
#pragma unroll
    for (int r = 0; r < 4; ++r) {
      float mx = fmaxf(fmaxf(s[0][r], s[1][r]), fmaxf(s[2][r], s[3][r]));
#pragma unroll
      for (int off = 8; off >= 1; off >>= 1) mx = fmaxf(mx, __shfl_xor(mx, off, 16));
      mnew[r] = fmaxf(mi[r], mx);
      alpha[r] = __expf(mi[r] - mnew[r]);
      mi[r] = mnew[r];
      rsum[r] = 0.f;
    }
#pragma unroll
    for (int nt = 0; nt < 4; ++nt) {
#pragma unroll
      for (int r = 0; r < 4; ++r) {
        float p = __expf(s[nt][r] - mnew[r]);
        rsum[r] += p;
        Pt[w][(lq * 4 + r) * 72 + nt * 16 + lr] = f2bf(p);  // C-layout -> LDS
      }
    }
#pragma unroll
    for (int r = 0; r < 4; ++r) {
      float t = rsum[r];
#pragma unroll
      for (int off = 8; off >= 1; off >>= 1) t += __shfl_xor(t, off, 16);
      li[r] = li[r] * alpha[r] + t;
    }
#pragma unroll
    for (int nt = 0; nt < 4; ++nt)
#pragma unroll
      for (int r = 0; r < 4; ++r) o[nt][r] *= alpha[r];

    // O += P @ V   (P re-read in A-layout; V^T gives B-layout reads)
    bf16x8 pf[2];
#pragma unroll
    for (int kb = 0; kb < 2; ++kb)
      pf[kb] = *(const bf16x8*)(&Pt[w][lr * 72 + kb * 32 + lq * 8]);
#pragma unroll
    for (int nt = 0; nt < 4; ++nt) {
      bf16x8 vf0 = *(const bf16x8*)(&Vt[(nt * 16 + lr) * 72 + lq * 8]);
      bf16x8 vf1 = *(const bf16x8*)(&Vt[(nt * 16 + lr) * 72 + 32 + lq * 8]);
      o[nt] = mfma16(pf[0], vf0, o[nt]);
      o[nt] = mfma16(pf[1], vf1, o[nt]);
    }
  }

  // write Y[b, t, h*64 + d]  (token-major for the proj GEMM)
#pragma unroll
  for (int nt = 0; nt < 4; ++nt) {
#pragma unroll
    for (int r = 0; r < 4; ++r) {
      int t_g = q0 + w * 16 + lq * 4 + r;
      int d = nt * 16 + lr;
      float v = o[nt][r] / li[r];
      Y[((size_t)(b * T + t_g)) * 1024 + h * 64 + d] = f2bf(v);
    }
  }
}

// ---------------- launch ----------------
extern "C" void kernel_launch(void* const* d_in, const int* in_sizes, int n_in,
                              void* d_out, int out_size, void* d_ws, size_t ws_size,
                              hipStream_t stream) {
  const float* x = (const float*)d_in[0];       // [4,2048,1024]
  const float* qkv_w = (const float*)d_in[1];   // [3072,1024]
  const float* qkv_b = (const float*)d_in[2];   // [3072]
  const float* proj_w = (const float*)d_in[3];  // [1024,1024]
  const float* proj_b = (const float*)d_in[4];  // [1024]
  float* out = (float*)d_out;                   // [4,2048,1024] fp32

  // workspace layout (bf16 elements); total ~92.3 MB
  unsigned short* ws = (unsigned short*)d_ws;
  unsigned short* xb = ws;                     // 8388608
  unsigned short* wqkv = xb + 8388608;         // 3145728
  unsigned short* wproj = wqkv + 3145728;      // 1048576
  unsigned short* Qb = wproj + 1048576;        // 8388608 [B,H,T,hd]
  unsigned short* Kb = Qb + 8388608;           // 8388608
  unsigned short* Vb = Kb + 8388608;           // 8388608
  unsigned short* Yb = Vb + 8388608;           // 8388608 [B*T, C]

  cvt_kernel<<<8388608 / 1024, 256, 0, stream>>>(x, xb, 8388608);
  cvt_kernel<<<3145728 / 1024, 256, 0, stream>>>(qkv_w, wqkv, 3145728);
  cvt_kernel<<<1048576 / 1024, 256, 0, stream>>>(proj_w, wproj, 1048576);

  gemm_bt<0><<<dim3(24, 64), 256, 0, stream>>>(xb, wqkv, qkv_b, nullptr, Qb, Kb, Vb,
                                               8192, 3072, 1024);
  attn_kernel<<<dim3(32, 16, 4), 256, 0, stream>>>(Qb, Kb, Vb, Yb);
  gemm_bt<1><<<dim3(8, 64), 256, 0, stream>>>(Yb, wproj, proj_b, out, nullptr, nullptr,
                                              nullptr, 8192, 1024, 1024);
}

// Round 2
// 458.668 us; speedup vs baseline: 1.0020x; 1.0020x over previous
//
#include <hip/hip_runtime.h>
#include <stdint.h>
#include <math.h>

#define DEVI __device__ __forceinline__

typedef __attribute__((ext_vector_type(8))) short bf16x8;
typedef __attribute__((ext_vector_type(4))) float f32x4;

DEVI unsigned short f2bf(float f) {
  union { float f; unsigned u; } v; v.f = f;
  unsigned u = v.u;
  u += 0x7fffu + ((u >> 16) & 1u);   // round-to-nearest-even
  return (unsigned short)(u >> 16);
}

DEVI f32x4 mfma16(bf16x8 a, bf16x8 b, f32x4 c) {
  return __builtin_amdgcn_mfma_f32_16x16x32_bf16(a, b, c, 0, 0, 0);
}

// async global->LDS, 16 B per lane; LDS dest = wave-uniform base + lane*16
DEVI void gld16(const unsigned short* g, unsigned short* l) {
  __builtin_amdgcn_global_load_lds(
      (const __attribute__((address_space(1))) unsigned int*)(uintptr_t)g,
      (__attribute__((address_space(3))) unsigned int*)(unsigned int)(uintptr_t)l,
      16, 0, 0);
}

// ---------------- fp32 -> bf16 convert ----------------
__global__ __launch_bounds__(256) void cvt_kernel(const float* __restrict__ in,
                                                  unsigned short* __restrict__ out, int n) {
  int i = (blockIdx.x * 256 + threadIdx.x) * 4;
  if (i < n) {
    float4 v = *(const float4*)(in + i);
    unsigned lo = f2bf(v.x) | ((unsigned)f2bf(v.y) << 16);
    unsigned hi = f2bf(v.z) | ((unsigned)f2bf(v.w) << 16);
    uint2 o; o.x = lo; o.y = hi;
    *(uint2*)(out + i) = o;
  }
}

// ---------------- GEMM: C[M,N] = A[M,K] * Bw[N,K]^T + bias ----------------
// MODE 0: scatter bf16 output to Q/K/V [B,H,T,hd]   MODE 1: fp32 output to Cf
template <int MODE>
__global__ __launch_bounds__(256) void gemm_bt(
    const unsigned short* __restrict__ A, const unsigned short* __restrict__ Bw,
    const float* __restrict__ bias, float* __restrict__ Cf,
    unsigned short* __restrict__ Qo, unsigned short* __restrict__ Ko,
    unsigned short* __restrict__ Vo, int M, int N, int K) {
  __shared__ unsigned short As[128 * 64];
  __shared__ unsigned short Bs[128 * 64];
  const int tid = threadIdx.x;
  const int lane = tid & 63;
  const int w = tid >> 6;
  const int wm = w & 1, wn = w >> 1;
  const int lr = lane & 15, lq = lane >> 4;
  const int m0 = blockIdx.y * 128;
  const int n0 = blockIdx.x * 128;
  const int l8r = lane >> 3;        // 0..7
  const int l8c = (lane & 7) << 3;  // 0..56

  f32x4 acc[4][4] = {};

  for (int kt = 0; kt < K; kt += 64) {
    __syncthreads();
    // stage A & B via async global->LDS (m97 pattern): 8 calls/wave, 1 KB each
#pragma unroll
    for (int i = 0; i < 4; ++i) {
      int c = w * 4 + i;            // 0..15, 8 rows per call
      int row = c * 8 + l8r;
      gld16(A + (size_t)(m0 + row) * K + kt + l8c, &As[c * 8 * 64]);
      gld16(Bw + (size_t)(n0 + row) * K + kt + l8c, &Bs[c * 8 * 64]);
    }
    __syncthreads();
#pragma unroll
    for (int kk = 0; kk < 64; kk += 32) {
      bf16x8 af[4], bfr[4];
#pragma unroll
      for (int mt = 0; mt < 4; ++mt)
        af[mt] = *(const bf16x8*)(&As[(wm * 64 + mt * 16 + lr) * 64 + kk + lq * 8]);
#pragma unroll
      for (int nt = 0; nt < 4; ++nt)
        bfr[nt] = *(const bf16x8*)(&Bs[(wn * 64 + nt * 16 + lr) * 64 + kk + lq * 8]);
#pragma unroll
      for (int mt = 0; mt < 4; ++mt)
#pragma unroll
        for (int nt = 0; nt < 4; ++nt)
          acc[mt][nt] = mfma16(af[mt], bfr[nt], acc[mt][nt]);
    }
  }

#pragma unroll
  for (int mt = 0; mt < 4; ++mt) {
#pragma unroll
    for (int nt = 0; nt < 4; ++nt) {
      int n_g = n0 + wn * 64 + nt * 16 + lr;
      float bv = bias[n_g];
#pragma unroll
      for (int r = 0; r < 4; ++r) {
        int m_g = m0 + wm * 64 + mt * 16 + lq * 4 + r;
        float v = acc[mt][nt][r] + bv;
        if (MODE == 1) {
          Cf[(size_t)m_g * N + n_g] = v;
        } else {
          int which = n_g >> 10;               // 0:Q 1:K 2:V  (uniform per block)
          int rem = n_g & 1023;
          int h = rem >> 6, d = rem & 63;
          int b = m_g >> 11, t = m_g & 2047;
          size_t idx = (((size_t)(b * 16 + h) * 2048) + t) * 64 + d;
          unsigned short* p = (which == 0) ? Qo : ((which == 1) ? Ko : Vo);
          p[idx] = f2bf(v);
        }
      }
    }
  }
}

// ---------------- flash attention (causal), Br=Bc=64, hd=64 ----------------
__global__ __launch_bounds__(256) void attn_kernel(
    const unsigned short* __restrict__ Q, const unsigned short* __restrict__ K,
    const unsigned short* __restrict__ V, unsigned short* __restrict__ Y) {
  constexpr int T = 2048, HD = 64, H = 16;
  __shared__ unsigned short Kt[64 * 72];      // K rows [kv][d], pad 8
  __shared__ unsigned short Vt[64 * 72];      // V^T    [d][kv], pad 8
  __shared__ unsigned short Pt[4][16 * 72];   // per-wave P, [qrow][kv]

  const int tid = threadIdx.x;
  const int lane = tid & 63;
  const int w = tid >> 6;
  const int lr = lane & 15, lq = lane >> 4;
  const int qt = 31 - blockIdx.x;  // heavy q-tiles dispatch first (tail = light)
  const int h = blockIdx.y;    // 0..15
  const int b = blockIdx.z;    // 0..3
  const size_t bh = (size_t)(b * H + h) * T * HD;
  const int q0 = qt * 64;

  // Q A-fragments in registers for the whole kernel
  bf16x8 qf[2];
  const int qrow = q0 + w * 16 + lr;
#pragma unroll
  for (int kb = 0; kb < 2; ++kb)
    qf[kb] = *(const bf16x8*)(Q + bh + (size_t)qrow * HD + kb * 32 + lq * 8);

  f32x4 o[4] = {};
  float mi[4], li[4];
#pragma unroll
  for (int r = 0; r < 4; ++r) { mi[r] = -INFINITY; li[r] = 0.f; }

  // K/V tile prefetch registers (2 float4 each = 16 B/thread/tile each)
  float4 kr[2], vr[2];
  const int krow = tid >> 3, kcb = (tid & 7) << 3;          // chunk 0 K coords
  const int krow1 = (256 + tid) >> 3;                        // chunk 1 K row
  const int vrow = tid & 63, vcb0 = ((tid >> 6) & 3) << 4;   // V: 2x 8-col chunks

  auto load_tile = [&](int jt) {
    const int c0 = jt * 64;
    kr[0] = *(const float4*)(K + bh + (size_t)(c0 + krow) * HD + kcb);
    kr[1] = *(const float4*)(K + bh + (size_t)(c0 + krow1) * HD + kcb);
    vr[0] = *(const float4*)(V + bh + (size_t)(c0 + vrow) * HD + (tid >> 6) * 8);
    vr[1] = *(const float4*)(V + bh + (size_t)(c0 + vrow) * HD + 32 + (tid >> 6) * 8);
  };
  load_tile(0);

  for (int jt = 0; jt <= qt; ++jt) {
    const int c0 = jt * 64;
    __syncthreads();   // previous tile's Kt/Vt reads done
    // regs -> LDS
    *(float4*)(&Kt[krow * 72 + kcb]) = kr[0];
    *(float4*)(&Kt[krow1 * 72 + kcb]) = kr[1];
    {
      const unsigned short* vp0 = (const unsigned short*)&vr[0];
      const unsigned short* vp1 = (const unsigned short*)&vr[1];
      int vc = (tid >> 6) * 8;
#pragma unroll
      for (int j = 0; j < 8; ++j) Vt[(vc + j) * 72 + vrow] = vp0[j];
#pragma unroll
      for (int j = 0; j < 8; ++j) Vt[(32 + vc + j) * 72 + vrow] = vp1[j];
    }
    __syncthreads();
    if (jt < qt) load_tile(jt + 1);   // async: latency hidden behind compute

    // S = Q K^T (wave handles 16 q-rows x 64 kv-cols)
    f32x4 s[4];
#pragma unroll
    for (int nt = 0; nt < 4; ++nt) {
      bf16x8 kf0 = *(const bf16x8*)(&Kt[(nt * 16 + lr) * 72 + lq * 8]);
      bf16x8 kf1 = *(const bf16x8*)(&Kt[(nt * 16 + lr) * 72 + 32 + lq * 8]);
      f32x4 z = {};
      z = mfma16(qf[0], kf0, z);
      s[nt] = mfma16(qf[1], kf1, z);
    }
    const bool diag = (jt == qt);
#pragma unroll
    for (int nt = 0; nt < 4; ++nt) {
#pragma unroll
      for (int r = 0; r < 4; ++r) {
        float sv = s[nt][r] * 0.125f;   // 1/sqrt(64)
        if (diag) {
          int kv_g = c0 + nt * 16 + lr;
          int q_g = q0 + w * 16 + lq * 4 + r;
          if (kv_g > q_g) sv = -INFINITY;
        }
        s[nt][r] = sv;
      }
    }
    // online softmax: row max, alpha, p, row sum
    float mnew[4], alpha[4], rsum[4];
#pragma unroll
    for (int r = 0; r < 4; ++r) {
      float mx = fmaxf(fmaxf(s[0][r], s[1][r]), fmaxf(s[2][r], s[3][r]));
#pragma unroll
      for (int off = 8; off >= 1; off >>= 1) mx = fmaxf(mx, __shfl_xor(mx, off, 16));
      mnew[r] = fmaxf(mi[r], mx);
      alpha[r] = __expf(mi[r] - mnew[r]);
      mi[r] = mnew[r];
      rsum[r] = 0.f;
    }
#pragma unroll
    for (int nt = 0; nt < 4; ++nt) {
#pragma unroll
      for (int r = 0; r < 4; ++r) {
        float p = __expf(s[nt][r] - mnew[r]);
        rsum[r] += p;
        Pt[w][(lq * 4 + r) * 72 + nt * 16 + lr] = f2bf(p);  // C-layout -> LDS
      }
    }
#pragma unroll
    for (int r = 0; r < 4; ++r) {
      float t = rsum[r];
#pragma unroll
      for (int off = 8; off >= 1; off >>= 1) t += __shfl_xor(t, off, 16);
      li[r] = li[r] * alpha[r] + t;
    }
#pragma unroll
    for (int nt = 0; nt < 4; ++nt)
#pragma unroll
      for (int r = 0; r < 4; ++r) o[nt][r] *= alpha[r];

    // O += P @ V   (P re-read in A-layout; V^T gives B-layout reads)
    bf16x8 pf[2];
#pragma unroll
    for (int kb = 0; kb < 2; ++kb)
      pf[kb] = *(const bf16x8*)(&Pt[w][lr * 72 + kb * 32 + lq * 8]);
#pragma unroll
    for (int nt = 0; nt < 4; ++nt) {
      bf16x8 vf0 = *(const bf16x8*)(&Vt[(nt * 16 + lr) * 72 + lq * 8]);
      bf16x8 vf1 = *(const bf16x8*)(&Vt[(nt * 16 + lr) * 72 + 32 + lq * 8]);
      o[nt] = mfma16(pf[0], vf0, o[nt]);
      o[nt] = mfma16(pf[1], vf1, o[nt]);
    }
  }

  // write Y[b, t, h*64 + d]  (token-major for the proj GEMM)
#pragma unroll
  for (int nt = 0; nt < 4; ++nt) {
#pragma unroll
    for (int r = 0; r < 4; ++r) {
      int t_g = q0 + w * 16 + lq * 4 + r;
      int d = nt * 16 + lr;
      float v = o[nt][r] / li[r];
      Y[((size_t)(b * T + t_g)) * 1024 + h * 64 + d] = f2bf(v);
    }
  }
}

// ---------------- launch ----------------
extern "C" void kernel_launch(void* const* d_in, const int* in_sizes, int n_in,
                              void* d_out, int out_size, void* d_ws, size_t ws_size,
                              hipStream_t stream) {
  const float* x = (const float*)d_in[0];       // [4,2048,1024]
  const float* qkv_w = (const float*)d_in[1];   // [3072,1024]
  const float* qkv_b = (const float*)d_in[2];   // [3072]
  const float* proj_w = (const float*)d_in[3];  // [1024,1024]
  const float* proj_b = (const float*)d_in[4];  // [1024]
  float* out = (float*)d_out;                   // [4,2048,1024] fp32

  // workspace layout (bf16 elements); total ~92.3 MB
  unsigned short* ws = (unsigned short*)d_ws;
  unsigned short* xb = ws;                     // 8388608
  unsigned short* wqkv = xb + 8388608;         // 3145728
  unsigned short* wproj = wqkv + 3145728;      // 1048576
  unsigned short* Qb = wproj + 1048576;        // 8388608 [B,H,T,hd]
  unsigned short* Kb = Qb + 8388608;           // 8388608
  unsigned short* Vb = Kb + 8388608;           // 8388608
  unsigned short* Yb = Vb + 8388608;           // 8388608 [B*T, C]

  cvt_kernel<<<8388608 / 1024, 256, 0, stream>>>(x, xb, 8388608);
  cvt_kernel<<<3145728 / 1024, 256, 0, stream>>>(qkv_w, wqkv, 3145728);
  cvt_kernel<<<1048576 / 1024, 256, 0, stream>>>(proj_w, wproj, 1048576);

  gemm_bt<0><<<dim3(24, 64), 256, 0, stream>>>(xb, wqkv, qkv_b, nullptr, Qb, Kb, Vb,
                                               8192, 3072, 1024);
  attn_kernel<<<dim3(32, 16, 4), 256, 0, stream>>>(Qb, Kb, Vb, Yb);
  gemm_bt<1><<<dim3(8, 64), 256, 0, stream>>>(Yb, wproj, proj_b, out, nullptr, nullptr,
                                              nullptr, 8192, 1024, 1024);
}

// Round 3
// 295.957 us; speedup vs baseline: 1.5529x; 1.5498x over previous
//
#include <hip/hip_runtime.h>
#include <stdint.h>
#include <math.h>

#define DEVI __device__ __forceinline__

typedef __attribute__((ext_vector_type(8))) short bf16x8;
typedef __attribute__((ext_vector_type(4))) float f32x4;

DEVI unsigned short f2bf(float f) {
  union { float f; unsigned u; } v; v.f = f;
  unsigned u = v.u;
  u += 0x7fffu + ((u >> 16) & 1u);   // round-to-nearest-even
  return (unsigned short)(u >> 16);
}

DEVI f32x4 mfma16(bf16x8 a, bf16x8 b, f32x4 c) {
  return __builtin_amdgcn_mfma_f32_16x16x32_bf16(a, b, c, 0, 0, 0);
}

// async global->LDS, 16 B per lane; LDS dest = wave-uniform base + lane*16
DEVI void gld16(const unsigned short* g, unsigned short* l) {
  __builtin_amdgcn_global_load_lds(
      (const __attribute__((address_space(1))) unsigned int*)(uintptr_t)g,
      (__attribute__((address_space(3))) unsigned int*)(unsigned int)(uintptr_t)l,
      16, 0, 0);
}

// ---------------- fp32 -> bf16 convert ----------------
__global__ __launch_bounds__(256) void cvt_kernel(const float* __restrict__ in,
                                                  unsigned short* __restrict__ out, int n) {
  int i = (blockIdx.x * 256 + threadIdx.x) * 4;
  if (i < n) {
    float4 v = *(const float4*)(in + i);
    unsigned lo = f2bf(v.x) | ((unsigned)f2bf(v.y) << 16);
    unsigned hi = f2bf(v.z) | ((unsigned)f2bf(v.w) << 16);
    uint2 o; o.x = lo; o.y = hi;
    *(uint2*)(out + i) = o;
  }
}

// ---------------- GEMM: C[M,N] = A[M,K] * Bw[N,K]^T + bias ----------------
template <int MODE>
__global__ __launch_bounds__(256) void gemm_bt(
    const unsigned short* __restrict__ A, const unsigned short* __restrict__ Bw,
    const float* __restrict__ bias, float* __restrict__ Cf,
    unsigned short* __restrict__ Qo, unsigned short* __restrict__ Ko,
    unsigned short* __restrict__ Vo, int M, int N, int K) {
  __shared__ unsigned short As[128 * 64];
  __shared__ unsigned short Bs[128 * 64];
  const int tid = threadIdx.x;
  const int lane = tid & 63;
  const int w = tid >> 6;
  const int wm = w & 1, wn = w >> 1;
  const int lr = lane & 15, lq = lane >> 4;
  const int m0 = blockIdx.y * 128;
  const int n0 = blockIdx.x * 128;
  const int l8r = lane >> 3;        // 0..7
  const int l8c = (lane & 7) << 3;  // 0..56

  f32x4 acc[4][4] = {};

  for (int kt = 0; kt < K; kt += 64) {
    __syncthreads();
#pragma unroll
    for (int i = 0; i < 4; ++i) {
      int c = w * 4 + i;            // 0..15, 8 rows per call
      int row = c * 8 + l8r;
      gld16(A + (size_t)(m0 + row) * K + kt + l8c, &As[c * 8 * 64]);
      gld16(Bw + (size_t)(n0 + row) * K + kt + l8c, &Bs[c * 8 * 64]);
    }
    __syncthreads();
#pragma unroll
    for (int kk = 0; kk < 64; kk += 32) {
      bf16x8 af[4], bfr[4];
#pragma unroll
      for (int mt = 0; mt < 4; ++mt)
        af[mt] = *(const bf16x8*)(&As[(wm * 64 + mt * 16 + lr) * 64 + kk + lq * 8]);
#pragma unroll
      for (int nt = 0; nt < 4; ++nt)
        bfr[nt] = *(const bf16x8*)(&Bs[(wn * 64 + nt * 16 + lr) * 64 + kk + lq * 8]);
#pragma unroll
      for (int mt = 0; mt < 4; ++mt)
#pragma unroll
        for (int nt = 0; nt < 4; ++nt)
          acc[mt][nt] = mfma16(af[mt], bfr[nt], acc[mt][nt]);
    }
  }

#pragma unroll
  for (int mt = 0; mt < 4; ++mt) {
#pragma unroll
    for (int nt = 0; nt < 4; ++nt) {
      int n_g = n0 + wn * 64 + nt * 16 + lr;
      float bv = bias[n_g];
#pragma unroll
      for (int r = 0; r < 4; ++r) {
        int m_g = m0 + wm * 64 + mt * 16 + lq * 4 + r;
        float v = acc[mt][nt][r] + bv;
        if (MODE == 1) {
          Cf[(size_t)m_g * N + n_g] = v;
        } else {
          int which = n_g >> 10;               // 0:Q 1:K 2:V
          int rem = n_g & 1023;
          int h = rem >> 6, d = rem & 63;
          int b = m_g >> 11, t = m_g & 2047;
          size_t idx = (((size_t)(b * 16 + h) * 2048) + t) * 64 + d;
          unsigned short* p = (which == 0) ? Qo : ((which == 1) ? Ko : Vo);
          p[idx] = f2bf(v);
        }
      }
    }
  }
}

// ------- flash attention (causal), S^T formulation, 128-row Q-tiles -------
// Block: 4 waves x 32 q-rows = 128 q-rows; processes paired q-tiles
// (pair, 15-pair) -> uniform 34 KV-iterations per block. Grid 512 blocks.
__global__ __launch_bounds__(256, 2) void attn_kernel(
    const unsigned short* __restrict__ Q, const unsigned short* __restrict__ K,
    const unsigned short* __restrict__ V, unsigned short* __restrict__ Y) {
  constexpr int T = 2048, HD = 64, H = 16;
  __shared__ unsigned short Kt[64 * 72];      // K rows [kv][d], pad 8
  __shared__ unsigned short Vt[64 * 72];      // V^T    [d][kv], pad 8
  __shared__ unsigned short Pt[4][32 * 72];   // per-wave P, [q][kv]

  const int tid = threadIdx.x;
  const int lane = tid & 63;
  const int w = tid >> 6;
  const int lr = lane & 15, lq = lane >> 4;
  const int pair = blockIdx.x;  // 0..7
  const int h = blockIdx.y;
  const int b = blockIdx.z;
  const size_t bh = (size_t)(b * H + h) * T * HD;
  const float SC = 0.125f * 1.44269504089f;   // 1/sqrt(64) * log2(e)

  // staging coords (same pattern as verified round-1 kernel)
  const int krow = tid >> 3, kcb = (tid & 7) << 3;
  const int vrow = tid & 63, vc = (tid >> 6) * 8;

  float4 kr[2], vr[2];
  auto load_tile = [&](int jt) {
    const int c0 = jt * 64;
    kr[0] = *(const float4*)(K + bh + (size_t)(c0 + krow) * HD + kcb);
    kr[1] = *(const float4*)(K + bh + (size_t)(c0 + 32 + krow) * HD + kcb);
    vr[0] = *(const float4*)(V + bh + (size_t)(c0 + vrow) * HD + vc);
    vr[1] = *(const float4*)(V + bh + (size_t)(c0 + vrow) * HD + 32 + vc);
  };
  load_tile(0);

  for (int phase = 0; phase < 2; ++phase) {
    const int qt = phase ? (15 - pair) : pair;
    const int q0 = qt * 128;
    const int nkv = 2 * qt + 2;
    const int qmin = q0 + w * 32;        // wave's min q-row
    const int qmax = qmin + 31;

    // Q B-fragments (q = lr within each 16-row set)
    bf16x8 qf[2][2];
#pragma unroll
    for (int qs = 0; qs < 2; ++qs)
#pragma unroll
      for (int kb = 0; kb < 2; ++kb)
        qf[qs][kb] = *(const bf16x8*)(Q + bh + (size_t)(q0 + w * 32 + qs * 16 + lr) * HD +
                                      kb * 32 + lq * 8);

    f32x4 o[2][4] = {};
    float mi[2] = {-INFINITY, -INFINITY}, li[2] = {0.f, 0.f};

    for (int jt = 0; jt < nkv; ++jt) {
      const int c0 = jt * 64;
      __syncthreads();   // previous tile's LDS reads done
      *(float4*)(&Kt[krow * 72 + kcb]) = kr[0];
      *(float4*)(&Kt[(32 + krow) * 72 + kcb]) = kr[1];
      {
        const unsigned short* vp0 = (const unsigned short*)&vr[0];
        const unsigned short* vp1 = (const unsigned short*)&vr[1];
#pragma unroll
        for (int j = 0; j < 8; ++j) Vt[(vc + j) * 72 + vrow] = vp0[j];
#pragma unroll
        for (int j = 0; j < 8; ++j) Vt[(32 + vc + j) * 72 + vrow] = vp1[j];
      }
      __syncthreads();
      // prefetch next tile (or phase-1's tile 0 at the seam)
      if (jt + 1 < nkv) load_tile(jt + 1);
      else if (phase == 0) load_tile(0);

      if (c0 > qmax) continue;           // wave-uniform: tile fully masked

      // S^T = K Q^T : rows kv, cols q
      f32x4 s[2][4];
#pragma unroll
      for (int nt = 0; nt < 4; ++nt) {
        bf16x8 kf0 = *(const bf16x8*)(&Kt[(nt * 16 + lr) * 72 + lq * 8]);
        bf16x8 kf1 = *(const bf16x8*)(&Kt[(nt * 16 + lr) * 72 + 32 + lq * 8]);
#pragma unroll
        for (int qs = 0; qs < 2; ++qs) {
          f32x4 z = {};
          z = mfma16(kf0, qf[qs][0], z);
          s[qs][nt] = mfma16(kf1, qf[qs][1], z);
        }
      }
      // scale (+ causal mask only near the diagonal; wave-uniform branch)
      if (c0 + 63 > qmin) {
#pragma unroll
        for (int qs = 0; qs < 2; ++qs) {
          int qg = q0 + w * 32 + qs * 16 + lr;
#pragma unroll
          for (int nt = 0; nt < 4; ++nt)
#pragma unroll
            for (int r = 0; r < 4; ++r) {
              int kvg = c0 + nt * 16 + lq * 4 + r;
              s[qs][nt][r] = (kvg > qg) ? -INFINITY : s[qs][nt][r] * SC;
            }
        }
      } else {
#pragma unroll
        for (int qs = 0; qs < 2; ++qs)
#pragma unroll
          for (int nt = 0; nt < 4; ++nt)
#pragma unroll
            for (int r = 0; r < 4; ++r) s[qs][nt][r] *= SC;
      }
      // online softmax, one q-row per lane per qs
#pragma unroll
      for (int qs = 0; qs < 2; ++qs) {
        float mx = -INFINITY;
#pragma unroll
        for (int nt = 0; nt < 4; ++nt) {
          float a = fmaxf(fmaxf(s[qs][nt][0], s[qs][nt][1]),
                          fmaxf(s[qs][nt][2], s[qs][nt][3]));
          mx = fmaxf(mx, a);
        }
        mx = fmaxf(mx, __shfl_xor(mx, 16));
        mx = fmaxf(mx, __shfl_xor(mx, 32));
        float mnew = fmaxf(mi[qs], mx);
        float alpha = __builtin_amdgcn_exp2f(mi[qs] - mnew);
        mi[qs] = mnew;
        float rs = 0.f;
#pragma unroll
        for (int nt = 0; nt < 4; ++nt) {
          ushort4 pk;
          float p0 = __builtin_amdgcn_exp2f(s[qs][nt][0] - mnew);
          float p1 = __builtin_amdgcn_exp2f(s[qs][nt][1] - mnew);
          float p2 = __builtin_amdgcn_exp2f(s[qs][nt][2] - mnew);
          float p3 = __builtin_amdgcn_exp2f(s[qs][nt][3] - mnew);
          rs += (p0 + p1) + (p2 + p3);
          pk.x = f2bf(p0); pk.y = f2bf(p1); pk.z = f2bf(p2); pk.w = f2bf(p3);
          *(ushort4*)(&Pt[w][(qs * 16 + lr) * 72 + nt * 16 + lq * 4]) = pk;
        }
        rs += __shfl_xor(rs, 16);
        rs += __shfl_xor(rs, 32);
        li[qs] = li[qs] * alpha + rs;
#pragma unroll
        for (int nt = 0; nt < 4; ++nt)
#pragma unroll
          for (int r = 0; r < 4; ++r) o[qs][nt][r] *= alpha;
      }
      // O^T += V^T P^T  (A = V^T frag, B = P^T frag)
      bf16x8 pf[2][2];
#pragma unroll
      for (int qs = 0; qs < 2; ++qs)
#pragma unroll
        for (int kb = 0; kb < 2; ++kb)
          pf[qs][kb] = *(const bf16x8*)(&Pt[w][(qs * 16 + lr) * 72 + kb * 32 + lq * 8]);
#pragma unroll
      for (int nt = 0; nt < 4; ++nt) {
        bf16x8 vf0 = *(const bf16x8*)(&Vt[(nt * 16 + lr) * 72 + lq * 8]);
        bf16x8 vf1 = *(const bf16x8*)(&Vt[(nt * 16 + lr) * 72 + 32 + lq * 8]);
#pragma unroll
        for (int qs = 0; qs < 2; ++qs) {
          o[qs][nt] = mfma16(vf0, pf[qs][0], o[qs][nt]);
          o[qs][nt] = mfma16(vf1, pf[qs][1], o[qs][nt]);
        }
      }
    }

    // epilogue: Y[b, t=q, h*64 + d], O^T layout: lane holds q=lr, d=nt*16+lq*4+r
#pragma unroll
    for (int qs = 0; qs < 2; ++qs) {
      float inv = 1.f / li[qs];
      int t_g = q0 + w * 32 + qs * 16 + lr;
#pragma unroll
      for (int nt = 0; nt < 4; ++nt) {
        ushort4 yv;
        yv.x = f2bf(o[qs][nt][0] * inv);
        yv.y = f2bf(o[qs][nt][1] * inv);
        yv.z = f2bf(o[qs][nt][2] * inv);
        yv.w = f2bf(o[qs][nt][3] * inv);
        *(ushort4*)(Y + ((size_t)(b * T + t_g)) * 1024 + h * 64 + nt * 16 + lq * 4) = yv;
      }
    }
  }
}

// ---------------- launch ----------------
extern "C" void kernel_launch(void* const* d_in, const int* in_sizes, int n_in,
                              void* d_out, int out_size, void* d_ws, size_t ws_size,
                              hipStream_t stream) {
  const float* x = (const float*)d_in[0];       // [4,2048,1024]
  const float* qkv_w = (const float*)d_in[1];   // [3072,1024]
  const float* qkv_b = (const float*)d_in[2];   // [3072]
  const float* proj_w = (const float*)d_in[3];  // [1024,1024]
  const float* proj_b = (const float*)d_in[4];  // [1024]
  float* out = (float*)d_out;                   // [4,2048,1024] fp32

  unsigned short* ws = (unsigned short*)d_ws;
  unsigned short* xb = ws;                     // 8388608
  unsigned short* wqkv = xb + 8388608;         // 3145728
  unsigned short* wproj = wqkv + 3145728;      // 1048576
  unsigned short* Qb = wproj + 1048576;        // 8388608 [B,H,T,hd]
  unsigned short* Kb = Qb + 8388608;           // 8388608
  unsigned short* Vb = Kb + 8388608;           // 8388608
  unsigned short* Yb = Vb + 8388608;           // 8388608 [B*T, C]

  cvt_kernel<<<8388608 / 1024, 256, 0, stream>>>(x, xb, 8388608);
  cvt_kernel<<<3145728 / 1024, 256, 0, stream>>>(qkv_w, wqkv, 3145728);
  cvt_kernel<<<1048576 / 1024, 256, 0, stream>>>(proj_w, wproj, 1048576);

  gemm_bt<0><<<dim3(24, 64), 256, 0, stream>>>(xb, wqkv, qkv_b, nullptr, Qb, Kb, Vb,
                                               8192, 3072, 1024);
  attn_kernel<<<dim3(8, 16, 4), 256, 0, stream>>>(Qb, Kb, Vb, Yb);
  gemm_bt<1><<<dim3(8, 64), 256, 0, stream>>>(Yb, wproj, proj_b, out, nullptr, nullptr,
                                              nullptr, 8192, 1024, 1024);
}